// Round 1
// baseline (2101.997 us; speedup 1.0000x reference)
//
#include <hip/hip_runtime.h>
#include <math.h>

typedef long long i64;

#define HW 16384
#define IMG_H 128
#define IMG_W 128
#define DIM 192
#define NHEADS 4
#define CH 48
#define OQKV 576
#define HID 510
#define H2 1020
#define NB 4
#define NSPLIT 64

// ---------------- LayerNorm over channel dim (per pixel) ----------------
__global__ __launch_bounds__(256) void ln_kernel(const float* __restrict__ x,
    const float* __restrict__ w, const float* __restrict__ b, float* __restrict__ y) {
  int p = blockIdx.x * 256 + threadIdx.x;   // pixel 0..16383
  const float* xp = x + p;
  float s = 0.f, ss = 0.f;
  #pragma unroll 4
  for (int c = 0; c < DIM; ++c) { float v = xp[(i64)c * HW]; s += v; ss += v * v; }
  float mu = s * (1.f / DIM);
  float var = ss * (1.f / DIM) - mu * mu;
  float rs = rsqrtf(var + 1e-5f);
  #pragma unroll 4
  for (int c = 0; c < DIM; ++c) {
    y[(i64)c * HW + p] = (xp[(i64)c * HW] - mu) * rs * w[c] + b[c];
  }
}

// ---------------- conv1x1 as GEMM: Out[o,n] = bias[o] + sum_c W[o,c]*In[c,n] (+Res) ----
__global__ __launch_bounds__(256) void gemm_conv(const float* __restrict__ Wm,
    const float* __restrict__ bias, const float* __restrict__ In,
    const float* __restrict__ Res, float* __restrict__ Out, int O, int C) {
  __shared__ float As[16][64];
  __shared__ float Bs[16][64];
  int tid = threadIdx.x;
  int tx = tid & 15, ty = tid >> 4;
  int obase = blockIdx.y * 64, nbase = blockIdx.x * 64;
  float acc[4][4] = {};
  for (int c0 = 0; c0 < C; c0 += 16) {
    // A tile: W[obase..+64) x [c0..+16)  (scalar loads: C may be 510, unaligned)
    {
      int mo = tid >> 2;            // 0..63
      int kc = (tid & 3) * 4;       // 0,4,8,12
      int o = obase + mo;
      #pragma unroll
      for (int i = 0; i < 4; ++i) {
        int c = c0 + kc + i;
        As[kc + i][mo] = (o < O && c < C) ? Wm[(i64)o * C + c] : 0.f;
      }
    }
    // B tile: In[c0..+16) x [nbase..+64)
    {
      int c = c0 + ty;
      int col = tx * 4;
      float4 vb = make_float4(0.f, 0.f, 0.f, 0.f);
      if (c < C) vb = *(const float4*)(In + (i64)c * HW + nbase + col);
      Bs[ty][col + 0] = vb.x; Bs[ty][col + 1] = vb.y;
      Bs[ty][col + 2] = vb.z; Bs[ty][col + 3] = vb.w;
    }
    __syncthreads();
    #pragma unroll
    for (int kk = 0; kk < 16; ++kk) {
      float4 a4 = *(const float4*)&As[kk][ty * 4];
      float4 b4 = *(const float4*)&Bs[kk][tx * 4];
      float av[4] = {a4.x, a4.y, a4.z, a4.w};
      float bv[4] = {b4.x, b4.y, b4.z, b4.w};
      #pragma unroll
      for (int i2 = 0; i2 < 4; ++i2)
        #pragma unroll
        for (int j2 = 0; j2 < 4; ++j2) acc[i2][j2] += av[i2] * bv[j2];
    }
    __syncthreads();
  }
  #pragma unroll
  for (int i2 = 0; i2 < 4; ++i2) {
    int o = obase + ty * 4 + i2;
    if (o >= O) continue;
    float bv = bias[o];
    #pragma unroll
    for (int j2 = 0; j2 < 4; ++j2) {
      int n = nbase + tx * 4 + j2;
      float v = acc[i2][j2] + bv;
      if (Res) v += Res[(i64)o * HW + n];
      Out[(i64)o * HW + n] = v;
    }
  }
}

// ---------------- depthwise 3x3 (SAME, zero pad) ----------------
__global__ __launch_bounds__(256) void dwconv_kernel(const float* __restrict__ in,
    const float* __restrict__ w9, const float* __restrict__ bs,
    float* __restrict__ out, int C) {
  int idx = blockIdx.x * 256 + threadIdx.x;
  if (idx >= C * HW) return;
  int c = idx >> 14;
  int rem = idx & 16383;
  int yy = rem >> 7, xx = rem & 127;
  const float* wp = w9 + c * 9;
  const float* ip = in + (i64)c * HW;
  float acc = bs[c];
  #pragma unroll
  for (int dy = -1; dy <= 1; ++dy) {
    int iy = yy + dy;
    if (iy < 0 || iy >= IMG_H) continue;
    #pragma unroll
    for (int dx = -1; dx <= 1; ++dx) {
      int ix = xx + dx;
      if (ix < 0 || ix >= IMG_W) continue;
      acc += wp[(dy + 1) * 3 + (dx + 1)] * ip[iy * IMG_W + ix];
    }
  }
  out[idx] = acc;
}

// ---------------- inverse L2 norms for q (ch 0..191) and k (ch 192..383) ----------------
__global__ __launch_bounds__(256) void l2inv_kernel(const float* __restrict__ qkv2,
    float* __restrict__ inv) {
  int which = blockIdx.x;   // 0..383 == channel index in qkv2
  const float* p = qkv2 + (i64)which * HW;
  float s = 0.f;
  for (int i = threadIdx.x; i < HW; i += 256) { float v = p[i]; s += v * v; }
  #pragma unroll
  for (int m = 32; m; m >>= 1) s += __shfl_xor(s, m);
  __shared__ float wsum[4];
  int lane = threadIdx.x & 63, wid = threadIdx.x >> 6;
  if (lane == 0) wsum[wid] = s;
  __syncthreads();
  if (threadIdx.x == 0) {
    float t = wsum[0] + wsum[1] + wsum[2] + wsum[3];
    inv[which] = 1.f / fmaxf(sqrtf(t), 1e-12f);
  }
}

// ---------------- q @ k^T split-K partials: part[h][sp][c*48+d] ----------------
__global__ __launch_bounds__(256) void attn_qk_kernel(const float* __restrict__ qkv2,
    float* __restrict__ part) {
  __shared__ float qs[48][128];
  __shared__ float ks[48][128];
  int h = blockIdx.x, sp = blockIdx.y;
  int n0 = sp * (HW / NSPLIT);     // 256 per split
  const float* qb = qkv2 + (i64)(h * CH) * HW + n0;
  const float* kb = qkv2 + (i64)(DIM + h * CH) * HW + n0;
  int tid = threadIdx.x;
  int c0 = (tid >> 4) * 3, d0 = (tid & 15) * 3;
  float acc[3][3] = {};
  for (int nn = 0; nn < 256; nn += 128) {
    for (int l = tid; l < 48 * 32; l += 256) {   // 1536 float4 loads (q+k)
      int r = l >> 5, j = (l & 31) * 4;
      *(float4*)&qs[r][j] = *(const float4*)(qb + (i64)r * HW + nn + j);
      *(float4*)&ks[r][j] = *(const float4*)(kb + (i64)r * HW + nn + j);
    }
    __syncthreads();
    #pragma unroll 2
    for (int j = 0; j < 128; j += 4) {
      float qv[3][4], kv[3][4];
      #pragma unroll
      for (int i = 0; i < 3; ++i) {
        float4 t = *(const float4*)&qs[c0 + i][j];
        qv[i][0] = t.x; qv[i][1] = t.y; qv[i][2] = t.z; qv[i][3] = t.w;
        float4 u = *(const float4*)&ks[d0 + i][j];
        kv[i][0] = u.x; kv[i][1] = u.y; kv[i][2] = u.z; kv[i][3] = u.w;
      }
      #pragma unroll
      for (int i = 0; i < 3; ++i)
        #pragma unroll
        for (int jj = 0; jj < 3; ++jj)
          #pragma unroll
          for (int e = 0; e < 4; ++e)
            acc[i][jj] += qv[i][e] * kv[jj][e];
    }
    __syncthreads();
  }
  float* pp = part + ((i64)(h * NSPLIT) + sp) * 2304;
  #pragma unroll
  for (int i = 0; i < 3; ++i)
    #pragma unroll
    for (int jj = 0; jj < 3; ++jj)
      pp[(c0 + i) * 48 + d0 + jj] = acc[i][jj];
}

// ---------------- reduce partials, scale by inv-norms*temp, softmax over d ----------------
__global__ __launch_bounds__(64) void attn_sm_kernel(const float* __restrict__ part,
    const float* __restrict__ inv, const float* __restrict__ temp,
    float* __restrict__ attn) {
  int h = blockIdx.x, c = blockIdx.y;
  int d = threadIdx.x;
  float logit = -1e30f;
  if (d < CH) {
    float s = 0.f;
    for (int sp = 0; sp < NSPLIT; ++sp)
      s += part[((i64)(h * NSPLIT) + sp) * 2304 + c * 48 + d];
    logit = s * inv[h * CH + c] * inv[DIM + h * CH + d] * temp[h];
  }
  float m = logit;
  #pragma unroll
  for (int mask = 32; mask; mask >>= 1) m = fmaxf(m, __shfl_xor(m, mask));
  float e = (d < CH) ? expf(logit - m) : 0.f;
  float ssum = e;
  #pragma unroll
  for (int mask = 32; mask; mask >>= 1) ssum += __shfl_xor(ssum, mask);
  if (d < CH) attn[(i64)h * 2304 + c * 48 + d] = e / ssum;
}

// ---------------- out[c,n] = sum_d attn[c,d] * v[d,n] ----------------
__global__ __launch_bounds__(256) void attn_v_kernel(const float* __restrict__ qkv2,
    const float* __restrict__ attnm, float* __restrict__ out) {
  __shared__ float as[CH * CH];
  int h = blockIdx.x, tile = blockIdx.y;
  for (int l = threadIdx.x; l < CH * CH; l += 256) as[l] = attnm[(i64)h * 2304 + l];
  __syncthreads();
  int n = tile * 256 + threadIdx.x;
  const float* vb = qkv2 + (i64)(2 * DIM + h * CH) * HW + n;
  float vreg[CH];
  #pragma unroll
  for (int d = 0; d < CH; ++d) vreg[d] = vb[(i64)d * HW];
  float* ob = out + (i64)(h * CH) * HW + n;
  #pragma unroll 4
  for (int c = 0; c < CH; ++c) {
    float acc = 0.f;
    const float* ar = &as[c * CH];
    #pragma unroll
    for (int d = 0; d < CH; ++d) acc += ar[d] * vreg[d];
    ob[(i64)c * HW] = acc;
  }
}

// ---------------- fused FFN dwconv3x3 + exact-GELU gating ----------------
__global__ __launch_bounds__(256) void dwgate_kernel(const float* __restrict__ h1,
    const float* __restrict__ w9, const float* __restrict__ bs,
    float* __restrict__ outg) {
  int idx = blockIdx.x * 256 + threadIdx.x;
  if (idx >= HID * HW) return;
  int c = idx >> 14, rem = idx & 16383;
  int yy = rem >> 7, xx = rem & 127;
  const float* w1 = w9 + c * 9;
  const float* w2 = w9 + (i64)(c + HID) * 9;
  const float* i1 = h1 + (i64)c * HW;
  const float* i2 = h1 + (i64)(c + HID) * HW;
  float a1 = bs[c], a2 = bs[c + HID];
  #pragma unroll
  for (int dy = -1; dy <= 1; ++dy) {
    int iy = yy + dy;
    if (iy < 0 || iy >= IMG_H) continue;
    #pragma unroll
    for (int dx = -1; dx <= 1; ++dx) {
      int ix = xx + dx;
      if (ix < 0 || ix >= IMG_W) continue;
      int off = iy * IMG_W + ix;
      int wi = (dy + 1) * 3 + (dx + 1);
      a1 += w1[wi] * i1[off];
      a2 += w2[wi] * i2[off];
    }
  }
  float g = 0.5f * a1 * (1.f + erff(a1 * 0.70710678118654752f));
  outg[idx] = g * a2;
}

extern "C" void kernel_launch(void* const* d_in, const int* in_sizes, int n_in,
                              void* d_out, int out_size, void* d_ws, size_t ws_size,
                              hipStream_t stream) {
  const float* x        = (const float*)d_in[0];
  const float* ln1_w    = (const float*)d_in[1];
  const float* ln1_b    = (const float*)d_in[2];
  const float* qkv_w    = (const float*)d_in[3];
  const float* qkv_b    = (const float*)d_in[4];
  const float* qkv_dw_w = (const float*)d_in[5];
  const float* qkv_dw_b = (const float*)d_in[6];
  const float* temp     = (const float*)d_in[7];
  const float* proj_w   = (const float*)d_in[8];
  const float* proj_b   = (const float*)d_in[9];
  const float* ln2_w    = (const float*)d_in[10];
  const float* ln2_b    = (const float*)d_in[11];
  const float* pin_w    = (const float*)d_in[12];
  const float* pin_b    = (const float*)d_in[13];
  const float* dw_w     = (const float*)d_in[14];
  const float* dw_b     = (const float*)d_in[15];
  const float* pout_w   = (const float*)d_in[16];
  const float* pout_b   = (const float*)d_in[17];
  float* out = (float*)d_out;
  float* ws  = (float*)d_ws;

  // workspace layout (floats)
  float* y       = ws;                            // 192*16384        = 3,145,728
  float* buf1    = y + (i64)DIM * HW;             // 1020*16384       = 16,711,680 (qkv1 / h1)
  float* buf2    = buf1 + (i64)H2 * HW;           // 576*16384        = 9,437,184 (qkv2 / gated)
  float* attnout = buf2 + (i64)OQKV * HW;         // 192*16384        = 3,145,728
  float* invn    = attnout + (i64)DIM * HW;       // 384
  float* attnm   = invn + 384;                    // 4*48*48          = 9,216
  float* part    = attnm + 9216;                  // 4*64*2304        = 589,824
  size_t need = (size_t)(part + 589824 - ws) * 4;
  if (ws_size < need) return;  // insufficient scratch — cannot compute

  for (int b = 0; b < NB; ++b) {
    const float* xb = x + (i64)b * DIM * HW;
    float* outb = out + (i64)b * DIM * HW;

    // ---- attention branch ----
    ln_kernel<<<HW / 256, 256, 0, stream>>>(xb, ln1_w, ln1_b, y);
    gemm_conv<<<dim3(HW / 64, OQKV / 64), 256, 0, stream>>>(qkv_w, qkv_b, y, nullptr, buf1, OQKV, DIM);
    dwconv_kernel<<<(OQKV * HW) / 256, 256, 0, stream>>>(buf1, qkv_dw_w, qkv_dw_b, buf2, OQKV);
    l2inv_kernel<<<2 * DIM, 256, 0, stream>>>(buf2, invn);
    attn_qk_kernel<<<dim3(NHEADS, NSPLIT), 256, 0, stream>>>(buf2, part);
    attn_sm_kernel<<<dim3(NHEADS, CH), 64, 0, stream>>>(part, invn, temp, attnm);
    attn_v_kernel<<<dim3(NHEADS, HW / 256), 256, 0, stream>>>(buf2, attnm, attnout);
    gemm_conv<<<dim3(HW / 64, DIM / 64), 256, 0, stream>>>(proj_w, proj_b, attnout, xb, outb, DIM, DIM);

    // ---- FFN branch ----
    ln_kernel<<<HW / 256, 256, 0, stream>>>(outb, ln2_w, ln2_b, y);
    gemm_conv<<<dim3(HW / 64, (H2 + 63) / 64), 256, 0, stream>>>(pin_w, pin_b, y, nullptr, buf1, H2, DIM);
    dwgate_kernel<<<(HID * HW) / 256, 256, 0, stream>>>(buf1, dw_w, dw_b, buf2);
    gemm_conv<<<dim3(HW / 64, DIM / 64), 256, 0, stream>>>(pout_w, pout_b, buf2, outb, outb, DIM, HID);
  }
}

// Round 2
// 1544.382 us; speedup vs baseline: 1.3611x; 1.3611x over previous
//
#include <hip/hip_runtime.h>
#include <math.h>

typedef long long i64;
typedef unsigned short u16;
typedef unsigned int u32;

#define HW 16384
#define IMG_H 128
#define IMG_W 128
#define DIM 192
#define NHEADS 4
#define CH 48
#define OQKV 576
#define HID 510
#define H2 1020
#define NB 4
#define NSPLIT 64

typedef __attribute__((ext_vector_type(8))) short short8v;
typedef __attribute__((ext_vector_type(4))) float float4v;

__device__ __forceinline__ u16 f2bf(float f) {
  union { float f; u32 u; } v; v.f = f;
  u32 r = v.u + 0x7FFF + ((v.u >> 16) & 1);
  return (u16)(r >> 16);
}

#define GLL16(gp, lp) __builtin_amdgcn_global_load_lds( \
    (const __attribute__((address_space(1))) u32*)(gp), \
    (__attribute__((address_space(3))) u32*)(lp), 16, 0, 0)

// ---------------- LayerNorm over channels; writes bf16 pixel-major [N,192] ----
__global__ __launch_bounds__(256) void ln_kernel(const float* __restrict__ x,
    const float* __restrict__ w, const float* __restrict__ b, u16* __restrict__ yT) {
  int p = blockIdx.x * 256 + threadIdx.x;
  const float* xp = x + p;
  float s = 0.f, ss = 0.f;
  #pragma unroll 4
  for (int c = 0; c < DIM; ++c) { float v = xp[(i64)c * HW]; s += v; ss += v * v; }
  float mu = s * (1.f / DIM);
  float var = ss * (1.f / DIM) - mu * mu;
  float rs = rsqrtf(var + 1e-5f);
  u16* yp = yT + (i64)p * DIM;
  #pragma unroll 4
  for (int c = 0; c < DIM; c += 4) {
    ushort4 u;
    u.x = f2bf((xp[(i64)(c + 0) * HW] - mu) * rs * w[c + 0] + b[c + 0]);
    u.y = f2bf((xp[(i64)(c + 1) * HW] - mu) * rs * w[c + 1] + b[c + 1]);
    u.z = f2bf((xp[(i64)(c + 2) * HW] - mu) * rs * w[c + 2] + b[c + 2]);
    u.w = f2bf((xp[(i64)(c + 3) * HW] - mu) * rs * w[c + 3] + b[c + 3]);
    *(ushort4*)(yp + c) = u;
  }
}

// ---------------- weight fp32 [O,C] -> bf16 [Mpad,Kpad] zero-padded ----------
__global__ __launch_bounds__(256) void wconv_kernel(const float* __restrict__ W,
    u16* __restrict__ Wb, int O, int C, int Kpad, int total) {
  int idx = blockIdx.x * 256 + threadIdx.x;
  if (idx >= total) return;
  int r = idx / Kpad, c = idx - r * Kpad;
  float v = (r < O && c < C) ? W[(i64)r * C + c] : 0.f;
  Wb[idx] = f2bf(v);
}

// ---------------- bf16 MFMA GEMM: Out[o,n] = bias[o] + sum_k A[o,k]*B[n,k] (+Res) ----
// A: bf16 [Mpad,K] row-major (weights, zero-padded). B: bf16 [16384,K] pixel-major.
// Tile 128x128x64, 4 waves, global_load_lds w/ source-side XOR swizzle.
__global__ __launch_bounds__(256) void gemm_bf16(const u16* __restrict__ A,
    const float* __restrict__ bias, const u16* __restrict__ B,
    const float* __restrict__ Res, float* __restrict__ Out, int O, int K) {
  __shared__ __align__(16) u16 lds[2 * 128 * 64];
  int tid = threadIdx.x;
  int lane = tid & 63, wave = tid >> 6;
  int wm = (wave >> 1) * 64, wn = (wave & 1) * 64;
  int obase = blockIdx.y * 128, nbase = blockIdx.x * 128;
  float4v acc[4][4];
  #pragma unroll
  for (int m = 0; m < 4; ++m)
    #pragma unroll
    for (int n = 0; n < 4; ++n) acc[m][n] = (float4v){0.f, 0.f, 0.f, 0.f};

  const u16* Abase = A + (i64)obase * K;
  const u16* Bbase = B + (i64)nbase * K;
  char* ldsA = (char*)&lds[0];
  char* ldsB = (char*)&lds[8192];
  int srow = wave * 8 + (lane >> 3);   // 0..31 within chunk
  int sj = lane & 7;

  for (int k0 = 0; k0 < K; k0 += 64) {
    #pragma unroll
    for (int iss = 0; iss < 4; ++iss) {
      int r = iss * 32 + srow;
      int kb = sj ^ (r & 7);
      GLL16(Abase + (i64)r * K + k0 + kb * 8, ldsA + iss * 4096 + wave * 1024);
      GLL16(Bbase + (i64)r * K + k0 + kb * 8, ldsB + iss * 4096 + wave * 1024);
    }
    __syncthreads();
    #pragma unroll
    for (int kk = 0; kk < 2; ++kk) {
      short8v af[4], bfr[4];
      #pragma unroll
      for (int m = 0; m < 4; ++m) {
        int r = wm + m * 16 + (lane & 15);
        int kb = kk * 4 + (lane >> 4);
        af[m] = *(const short8v*)(ldsA + r * 128 + ((kb ^ (r & 7)) << 4));
      }
      #pragma unroll
      for (int n = 0; n < 4; ++n) {
        int r = wn + n * 16 + (lane & 15);
        int kb = kk * 4 + (lane >> 4);
        bfr[n] = *(const short8v*)(ldsB + r * 128 + ((kb ^ (r & 7)) << 4));
      }
      #pragma unroll
      for (int m = 0; m < 4; ++m)
        #pragma unroll
        for (int n = 0; n < 4; ++n)
          acc[m][n] = __builtin_amdgcn_mfma_f32_16x16x32_bf16(af[m], bfr[n], acc[m][n], 0, 0, 0);
    }
    __syncthreads();
  }

  int rowq = lane >> 4, coln = lane & 15;
  #pragma unroll
  for (int m = 0; m < 4; ++m) {
    #pragma unroll
    for (int reg = 0; reg < 4; ++reg) {
      int o = obase + wm + m * 16 + rowq * 4 + reg;
      if (o >= O) continue;
      float bv = bias[o];
      #pragma unroll
      for (int n = 0; n < 4; ++n) {
        int nn = nbase + wn + n * 16 + coln;
        float v = acc[m][n][reg] + bv;
        if (Res) v += Res[(i64)o * HW + nn];
        Out[(i64)o * HW + nn] = v;
      }
    }
  }
}

// ---------------- depthwise 3x3 (SAME, zero pad), fp32 ----------------
__global__ __launch_bounds__(256) void dwconv_kernel(const float* __restrict__ in,
    const float* __restrict__ w9, const float* __restrict__ bs,
    float* __restrict__ out, int C) {
  int idx = blockIdx.x * 256 + threadIdx.x;
  if (idx >= C * HW) return;
  int c = idx >> 14;
  int rem = idx & 16383;
  int yy = rem >> 7, xx = rem & 127;
  const float* wp = w9 + c * 9;
  const float* ip = in + (i64)c * HW;
  float acc = bs[c];
  #pragma unroll
  for (int dy = -1; dy <= 1; ++dy) {
    int iy = yy + dy;
    if (iy < 0 || iy >= IMG_H) continue;
    #pragma unroll
    for (int dx = -1; dx <= 1; ++dx) {
      int ix = xx + dx;
      if (ix < 0 || ix >= IMG_W) continue;
      acc += wp[(dy + 1) * 3 + (dx + 1)] * ip[iy * IMG_W + ix];
    }
  }
  out[idx] = acc;
}

// ---------------- inverse L2 norms for q,k channels ----------------
__global__ __launch_bounds__(256) void l2inv_kernel(const float* __restrict__ qkv2,
    float* __restrict__ inv) {
  int which = blockIdx.x;
  const float* p = qkv2 + (i64)which * HW;
  float s = 0.f;
  for (int i = threadIdx.x; i < HW; i += 256) { float v = p[i]; s += v * v; }
  #pragma unroll
  for (int m = 32; m; m >>= 1) s += __shfl_xor(s, m);
  __shared__ float wsum[4];
  int lane = threadIdx.x & 63, wid = threadIdx.x >> 6;
  if (lane == 0) wsum[wid] = s;
  __syncthreads();
  if (threadIdx.x == 0) {
    float t = wsum[0] + wsum[1] + wsum[2] + wsum[3];
    inv[which] = 1.f / fmaxf(sqrtf(t), 1e-12f);
  }
}

// ---------------- q @ k^T split-K partials ----------------
__global__ __launch_bounds__(256) void attn_qk_kernel(const float* __restrict__ qkv2,
    float* __restrict__ part) {
  __shared__ float qs[48][128];
  __shared__ float ks[48][128];
  int h = blockIdx.x, sp = blockIdx.y;
  int n0 = sp * (HW / NSPLIT);
  const float* qb = qkv2 + (i64)(h * CH) * HW + n0;
  const float* kb = qkv2 + (i64)(DIM + h * CH) * HW + n0;
  int tid = threadIdx.x;
  int c0 = (tid >> 4) * 3, d0 = (tid & 15) * 3;
  float acc[3][3] = {};
  for (int nn = 0; nn < 256; nn += 128) {
    for (int l = tid; l < 48 * 32; l += 256) {
      int r = l >> 5, j = (l & 31) * 4;
      *(float4*)&qs[r][j] = *(const float4*)(qb + (i64)r * HW + nn + j);
      *(float4*)&ks[r][j] = *(const float4*)(kb + (i64)r * HW + nn + j);
    }
    __syncthreads();
    #pragma unroll 2
    for (int j = 0; j < 128; j += 4) {
      float qv[3][4], kv[3][4];
      #pragma unroll
      for (int i = 0; i < 3; ++i) {
        float4 t = *(const float4*)&qs[c0 + i][j];
        qv[i][0] = t.x; qv[i][1] = t.y; qv[i][2] = t.z; qv[i][3] = t.w;
        float4 u = *(const float4*)&ks[d0 + i][j];
        kv[i][0] = u.x; kv[i][1] = u.y; kv[i][2] = u.z; kv[i][3] = u.w;
      }
      #pragma unroll
      for (int i = 0; i < 3; ++i)
        #pragma unroll
        for (int jj = 0; jj < 3; ++jj)
          #pragma unroll
          for (int e = 0; e < 4; ++e)
            acc[i][jj] += qv[i][e] * kv[jj][e];
    }
    __syncthreads();
  }
  float* pp = part + ((i64)(h * NSPLIT) + sp) * 2304;
  #pragma unroll
  for (int i = 0; i < 3; ++i)
    #pragma unroll
    for (int jj = 0; jj < 3; ++jj)
      pp[(c0 + i) * 48 + d0 + jj] = acc[i][jj];
}

// ---------------- reduce partials, scale, softmax ----------------
__global__ __launch_bounds__(64) void attn_sm_kernel(const float* __restrict__ part,
    const float* __restrict__ inv, const float* __restrict__ temp,
    float* __restrict__ attn) {
  int h = blockIdx.x, c = blockIdx.y;
  int d = threadIdx.x;
  float logit = -1e30f;
  if (d < CH) {
    float s = 0.f;
    for (int sp = 0; sp < NSPLIT; ++sp)
      s += part[((i64)(h * NSPLIT) + sp) * 2304 + c * 48 + d];
    logit = s * inv[h * CH + c] * inv[DIM + h * CH + d] * temp[h];
  }
  float m = logit;
  #pragma unroll
  for (int mask = 32; mask; mask >>= 1) m = fmaxf(m, __shfl_xor(m, mask));
  float e = (d < CH) ? expf(logit - m) : 0.f;
  float ssum = e;
  #pragma unroll
  for (int mask = 32; mask; mask >>= 1) ssum += __shfl_xor(ssum, mask);
  if (d < CH) attn[(i64)h * 2304 + c * 48 + d] = e / ssum;
}

// ---------------- out = attn @ v ; writes bf16 pixel-major [N,192] ----------------
__global__ __launch_bounds__(256) void attn_v_kernel(const float* __restrict__ qkv2,
    const float* __restrict__ attnm, u16* __restrict__ outT) {
  __shared__ float as[CH * CH];
  int h = blockIdx.x, tile = blockIdx.y;
  for (int l = threadIdx.x; l < CH * CH; l += 256) as[l] = attnm[(i64)h * 2304 + l];
  __syncthreads();
  int n = tile * 256 + threadIdx.x;
  const float* vb = qkv2 + (i64)(2 * DIM + h * CH) * HW + n;
  float vreg[CH];
  #pragma unroll
  for (int d = 0; d < CH; ++d) vreg[d] = vb[(i64)d * HW];
  u16* ob = outT + (i64)n * DIM + h * CH;
  #pragma unroll 2
  for (int c = 0; c < CH; c += 4) {
    float a0 = 0.f, a1 = 0.f, a2 = 0.f, a3 = 0.f;
    const float* r0 = &as[(c + 0) * CH];
    const float* r1 = &as[(c + 1) * CH];
    const float* r2 = &as[(c + 2) * CH];
    const float* r3 = &as[(c + 3) * CH];
    #pragma unroll
    for (int d = 0; d < CH; ++d) {
      float vv = vreg[d];
      a0 += r0[d] * vv; a1 += r1[d] * vv; a2 += r2[d] * vv; a3 += r3[d] * vv;
    }
    ushort4 u; u.x = f2bf(a0); u.y = f2bf(a1); u.z = f2bf(a2); u.w = f2bf(a3);
    *(ushort4*)(ob + c) = u;
  }
}

// ---------------- fused FFN dwconv3x3 + exact-GELU gating (fp32 out [510,N]) ----
__global__ __launch_bounds__(256) void dwgate_kernel(const float* __restrict__ h1,
    const float* __restrict__ w9, const float* __restrict__ bs,
    float* __restrict__ outg) {
  int idx = blockIdx.x * 256 + threadIdx.x;
  if (idx >= HID * HW) return;
  int c = idx >> 14, rem = idx & 16383;
  int yy = rem >> 7, xx = rem & 127;
  const float* w1 = w9 + c * 9;
  const float* w2 = w9 + (i64)(c + HID) * 9;
  const float* i1 = h1 + (i64)c * HW;
  const float* i2 = h1 + (i64)(c + HID) * HW;
  float a1 = bs[c], a2 = bs[c + HID];
  #pragma unroll
  for (int dy = -1; dy <= 1; ++dy) {
    int iy = yy + dy;
    if (iy < 0 || iy >= IMG_H) continue;
    #pragma unroll
    for (int dx = -1; dx <= 1; ++dx) {
      int ix = xx + dx;
      if (ix < 0 || ix >= IMG_W) continue;
      int off = iy * IMG_W + ix;
      int wi = (dy + 1) * 3 + (dx + 1);
      a1 += w1[wi] * i1[off];
      a2 += w2[wi] * i2[off];
    }
  }
  float g = 0.5f * a1 * (1.f + erff(a1 * 0.70710678118654752f));
  outg[idx] = g * a2;
}

// ---------------- fp32 [510,N] -> bf16 [N,512] (pad K to 512 with zeros) -----
__global__ __launch_bounds__(256) void transp_kernel(const float* __restrict__ in,
    u16* __restrict__ out) {
  __shared__ u16 t[64][136];
  int p0 = blockIdx.x * 64;
  int tid = threadIdx.x;
  for (int c0 = 0; c0 < 512; c0 += 128) {
    #pragma unroll 4
    for (int i = 0; i < 32; ++i) {
      int c = (tid >> 6) + i * 4;       // 0..127
      int p = tid & 63;
      int cc = c0 + c;
      float v = (cc < HID) ? in[(i64)cc * HW + p0 + p] : 0.f;
      t[p][c] = f2bf(v);
    }
    __syncthreads();
    #pragma unroll
    for (int i = 0; i < 4; ++i) {
      int p = (tid >> 4) + i * 16;
      int c8 = (tid & 15) * 8;
      *(uint4*)(out + (i64)(p0 + p) * 512 + c0 + c8) = *(const uint4*)&t[p][c8];
    }
    __syncthreads();
  }
}

extern "C" void kernel_launch(void* const* d_in, const int* in_sizes, int n_in,
                              void* d_out, int out_size, void* d_ws, size_t ws_size,
                              hipStream_t stream) {
  const float* x        = (const float*)d_in[0];
  const float* ln1_w    = (const float*)d_in[1];
  const float* ln1_b    = (const float*)d_in[2];
  const float* qkv_w    = (const float*)d_in[3];
  const float* qkv_b    = (const float*)d_in[4];
  const float* qkv_dw_w = (const float*)d_in[5];
  const float* qkv_dw_b = (const float*)d_in[6];
  const float* temp     = (const float*)d_in[7];
  const float* proj_w   = (const float*)d_in[8];
  const float* proj_b   = (const float*)d_in[9];
  const float* ln2_w    = (const float*)d_in[10];
  const float* ln2_b    = (const float*)d_in[11];
  const float* pin_w    = (const float*)d_in[12];
  const float* pin_b    = (const float*)d_in[13];
  const float* dw_w     = (const float*)d_in[14];
  const float* dw_b     = (const float*)d_in[15];
  const float* pout_w   = (const float*)d_in[16];
  const float* pout_b   = (const float*)d_in[17];
  float* out = (float*)d_out;
  float* ws  = (float*)d_ws;

  // workspace layout
  float* buf1f = ws;                               // 1020*16384 fp32 (qkv1 / h1)
  float* buf2f = buf1f + (i64)H2 * HW;             // 576*16384 fp32 (qkv2 / gated)
  u16*   yT    = (u16*)(buf2f + (i64)OQKV * HW);   // 16384*192 bf16
  u16*   Wq    = yT + (i64)HW * DIM;               // 640*192
  u16*   Wpj   = Wq + 640 * 192;                   // 256*192
  u16*   Wpi   = Wpj + 256 * 192;                  // 1024*192
  u16*   Wpo   = Wpi + 1024 * 192;                 // 256*512
  float* invn  = (float*)(Wpo + 256 * 512);        // 384
  float* attnm = invn + 384;                       // 9216
  float* part  = attnm + 9216;                     // 4*64*2304
  u16* attnoutT = (u16*)buf1f;   // alias: live only attn_v -> proj gemm
  u16* gatedT   = (u16*)buf1f;   // alias: live only transp -> pout gemm
  size_t need = (size_t)((char*)(part + 589824) - (char*)ws);
  if (ws_size < need) return;

  // weight conversions (per launch; deterministic)
  wconv_kernel<<<(640 * 192 + 255) / 256, 256, 0, stream>>>(qkv_w, Wq, OQKV, DIM, DIM, 640 * 192);
  wconv_kernel<<<(256 * 192 + 255) / 256, 256, 0, stream>>>(proj_w, Wpj, DIM, DIM, DIM, 256 * 192);
  wconv_kernel<<<(1024 * 192 + 255) / 256, 256, 0, stream>>>(pin_w, Wpi, H2, DIM, DIM, 1024 * 192);
  wconv_kernel<<<(256 * 512 + 255) / 256, 256, 0, stream>>>(pout_w, Wpo, DIM, HID, 512, 256 * 512);

  for (int b = 0; b < NB; ++b) {
    const float* xb = x + (i64)b * DIM * HW;
    float* outb = out + (i64)b * DIM * HW;

    // ---- attention branch ----
    ln_kernel<<<HW / 256, 256, 0, stream>>>(xb, ln1_w, ln1_b, yT);
    gemm_bf16<<<dim3(HW / 128, 640 / 128), 256, 0, stream>>>(Wq, qkv_b, yT, nullptr, buf1f, OQKV, DIM);
    dwconv_kernel<<<(OQKV * HW) / 256, 256, 0, stream>>>(buf1f, qkv_dw_w, qkv_dw_b, buf2f, OQKV);
    l2inv_kernel<<<2 * DIM, 256, 0, stream>>>(buf2f, invn);
    attn_qk_kernel<<<dim3(NHEADS, NSPLIT), 256, 0, stream>>>(buf2f, part);
    attn_sm_kernel<<<dim3(NHEADS, CH), 64, 0, stream>>>(part, invn, temp, attnm);
    attn_v_kernel<<<dim3(NHEADS, HW / 256), 256, 0, stream>>>(buf2f, attnm, attnoutT);
    gemm_bf16<<<dim3(HW / 128, 256 / 128), 256, 0, stream>>>(Wpj, proj_b, attnoutT, xb, outb, DIM, DIM);

    // ---- FFN branch ----
    ln_kernel<<<HW / 256, 256, 0, stream>>>(outb, ln2_w, ln2_b, yT);
    gemm_bf16<<<dim3(HW / 128, 1024 / 128), 256, 0, stream>>>(Wpi, pin_b, yT, nullptr, buf1f, H2, DIM);
    dwgate_kernel<<<(HID * HW) / 256, 256, 0, stream>>>(buf1f, dw_w, dw_b, buf2f);
    transp_kernel<<<HW / 64, 256, 0, stream>>>(buf2f, gatedT);
    gemm_bf16<<<dim3(HW / 128, 256 / 128), 256, 0, stream>>>(Wpo, pout_b, gatedT, outb, outb, DIM, 512);
  }
}

// Round 3
// 1211.617 us; speedup vs baseline: 1.7349x; 1.2746x over previous
//
#include <hip/hip_runtime.h>
#include <math.h>

typedef long long i64;
typedef unsigned short u16;
typedef unsigned int u32;

#define HW 16384
#define IMG_H 128
#define IMG_W 128
#define DIM 192
#define NHEADS 4
#define CH 48
#define OQKV 576
#define HID 510
#define H2 1020
#define NB 4
#define NSPLIT 64

typedef __attribute__((ext_vector_type(8))) short short8v;
typedef __attribute__((ext_vector_type(4))) float float4v;

__device__ __forceinline__ u16 f2bf(float f) {
  union { float f; u32 u; } v; v.f = f;
  u32 r = v.u + 0x7FFF + ((v.u >> 16) & 1);
  return (u16)(r >> 16);
}

#define GLL16(gp, lp) __builtin_amdgcn_global_load_lds( \
    (const __attribute__((address_space(1))) u32*)(gp), \
    (__attribute__((address_space(3))) u32*)(lp), 16, 0, 0)

// ---------------- LayerNorm over channels; writes bf16 pixel-major [N,192] ----
// block = 32 pixels x 8 channel-groups (24 ch each); grid = HW/32 = 512 blocks.
#define LNP 32
#define LNG 8
#define LNC 24
__global__ __launch_bounds__(256) void ln_kernel(const float* __restrict__ x,
    const float* __restrict__ w, const float* __restrict__ b, u16* __restrict__ yT) {
  __shared__ float red[2][LNG][LNP];
  __shared__ float murs[2][LNP];
  int tid = threadIdx.x;
  int g = tid >> 5;          // 0..7
  int p = tid & 31;          // 0..31
  int pix = blockIdx.x * LNP + p;
  const float* xp = x + pix;
  float v[LNC];
  float s = 0.f, ss = 0.f;
  #pragma unroll
  for (int i = 0; i < LNC; ++i) {
    float t = xp[(i64)(g * LNC + i) * HW];
    v[i] = t; s += t; ss += t * t;
  }
  red[0][g][p] = s; red[1][g][p] = ss;
  __syncthreads();
  if (tid < LNP) {
    float S = 0.f, SS = 0.f;
    #pragma unroll
    for (int gg = 0; gg < LNG; ++gg) { S += red[0][gg][tid]; SS += red[1][gg][tid]; }
    float mu = S * (1.f / DIM);
    float var = SS * (1.f / DIM) - mu * mu;
    murs[0][tid] = mu;
    murs[1][tid] = rsqrtf(var + 1e-5f);
  }
  __syncthreads();
  float mu = murs[0][p], rs = murs[1][p];
  u16* yp = yT + (i64)pix * DIM + g * LNC;
  #pragma unroll
  for (int i = 0; i < LNC; i += 4) {
    int c = g * LNC + i;
    ushort4 u;
    u.x = f2bf((v[i + 0] - mu) * rs * w[c + 0] + b[c + 0]);
    u.y = f2bf((v[i + 1] - mu) * rs * w[c + 1] + b[c + 1]);
    u.z = f2bf((v[i + 2] - mu) * rs * w[c + 2] + b[c + 2]);
    u.w = f2bf((v[i + 3] - mu) * rs * w[c + 3] + b[c + 3]);
    *(ushort4*)(yp + i) = u;
  }
}

// ---------------- weight fp32 [O,C] -> bf16 [Mpad,Kpad] zero-padded ----------
__global__ __launch_bounds__(256) void wconv_kernel(const float* __restrict__ W,
    u16* __restrict__ Wb, int O, int C, int Kpad, int total) {
  int idx = blockIdx.x * 256 + threadIdx.x;
  if (idx >= total) return;
  int r = idx / Kpad, c = idx - r * Kpad;
  float v = (r < O && c < C) ? W[(i64)r * C + c] : 0.f;
  Wb[idx] = f2bf(v);
}

// ---------------- bf16 MFMA GEMM: Out[o,n] = bias[o] + sum_k A[o,k]*B[n,k] (+Res) ----
__global__ __launch_bounds__(256) void gemm_bf16(const u16* __restrict__ A,
    const float* __restrict__ bias, const u16* __restrict__ B,
    const float* __restrict__ Res, float* __restrict__ Out, int O, int K) {
  __shared__ __align__(16) u16 lds[2 * 128 * 64];
  int tid = threadIdx.x;
  int lane = tid & 63, wave = tid >> 6;
  int wm = (wave >> 1) * 64, wn = (wave & 1) * 64;
  int obase = blockIdx.y * 128, nbase = blockIdx.x * 128;
  float4v acc[4][4];
  #pragma unroll
  for (int m = 0; m < 4; ++m)
    #pragma unroll
    for (int n = 0; n < 4; ++n) acc[m][n] = (float4v){0.f, 0.f, 0.f, 0.f};

  const u16* Abase = A + (i64)obase * K;
  const u16* Bbase = B + (i64)nbase * K;
  char* ldsA = (char*)&lds[0];
  char* ldsB = (char*)&lds[8192];
  int srow = wave * 8 + (lane >> 3);
  int sj = lane & 7;

  for (int k0 = 0; k0 < K; k0 += 64) {
    #pragma unroll
    for (int iss = 0; iss < 4; ++iss) {
      int r = iss * 32 + srow;
      int kb = sj ^ (r & 7);
      GLL16(Abase + (i64)r * K + k0 + kb * 8, ldsA + iss * 4096 + wave * 1024);
      GLL16(Bbase + (i64)r * K + k0 + kb * 8, ldsB + iss * 4096 + wave * 1024);
    }
    __syncthreads();
    #pragma unroll
    for (int kk = 0; kk < 2; ++kk) {
      short8v af[4], bfr[4];
      #pragma unroll
      for (int m = 0; m < 4; ++m) {
        int r = wm + m * 16 + (lane & 15);
        int kb = kk * 4 + (lane >> 4);
        af[m] = *(const short8v*)(ldsA + r * 128 + ((kb ^ (r & 7)) << 4));
      }
      #pragma unroll
      for (int n = 0; n < 4; ++n) {
        int r = wn + n * 16 + (lane & 15);
        int kb = kk * 4 + (lane >> 4);
        bfr[n] = *(const short8v*)(ldsB + r * 128 + ((kb ^ (r & 7)) << 4));
      }
      #pragma unroll
      for (int m = 0; m < 4; ++m)
        #pragma unroll
        for (int n = 0; n < 4; ++n)
          acc[m][n] = __builtin_amdgcn_mfma_f32_16x16x32_bf16(af[m], bfr[n], acc[m][n], 0, 0, 0);
    }
    __syncthreads();
  }

  int rowq = lane >> 4, coln = lane & 15;
  #pragma unroll
  for (int m = 0; m < 4; ++m) {
    #pragma unroll
    for (int reg = 0; reg < 4; ++reg) {
      int o = obase + wm + m * 16 + rowq * 4 + reg;
      if (o >= O) continue;
      float bv = bias[o];
      #pragma unroll
      for (int n = 0; n < 4; ++n) {
        int nn = nbase + wn + n * 16 + coln;
        float v = acc[m][n][reg] + bv;
        if (Res) v += Res[(i64)o * HW + nn];
        Out[(i64)o * HW + nn] = v;
      }
    }
  }
}

// ---------------- depthwise 3x3 (SAME, zero pad), fp32 ----------------
__global__ __launch_bounds__(256) void dwconv_kernel(const float* __restrict__ in,
    const float* __restrict__ w9, const float* __restrict__ bs,
    float* __restrict__ out, int C) {
  int idx = blockIdx.x * 256 + threadIdx.x;
  if (idx >= C * HW) return;
  int c = idx >> 14;
  int rem = idx & 16383;
  int yy = rem >> 7, xx = rem & 127;
  const float* wp = w9 + c * 9;
  const float* ip = in + (i64)c * HW;
  float acc = bs[c];
  #pragma unroll
  for (int dy = -1; dy <= 1; ++dy) {
    int iy = yy + dy;
    if (iy < 0 || iy >= IMG_H) continue;
    #pragma unroll
    for (int dx = -1; dx <= 1; ++dx) {
      int ix = xx + dx;
      if (ix < 0 || ix >= IMG_W) continue;
      acc += wp[(dy + 1) * 3 + (dx + 1)] * ip[iy * IMG_W + ix];
    }
  }
  out[idx] = acc;
}

// ---------------- inverse L2 norms for q,k channels ----------------
__global__ __launch_bounds__(256) void l2inv_kernel(const float* __restrict__ qkv2,
    float* __restrict__ inv) {
  int which = blockIdx.x;
  const float* p = qkv2 + (i64)which * HW;
  float s = 0.f;
  for (int i = threadIdx.x; i < HW; i += 256) { float v = p[i]; s += v * v; }
  #pragma unroll
  for (int m = 32; m; m >>= 1) s += __shfl_xor(s, m);
  __shared__ float wsum[4];
  int lane = threadIdx.x & 63, wid = threadIdx.x >> 6;
  if (lane == 0) wsum[wid] = s;
  __syncthreads();
  if (threadIdx.x == 0) {
    float t = wsum[0] + wsum[1] + wsum[2] + wsum[3];
    inv[which] = 1.f / fmaxf(sqrtf(t), 1e-12f);
  }
}

// ---------------- q @ k^T split-K partials ----------------
__global__ __launch_bounds__(256) void attn_qk_kernel(const float* __restrict__ qkv2,
    float* __restrict__ part) {
  __shared__ float qs[48][128];
  __shared__ float ks[48][128];
  int h = blockIdx.x, sp = blockIdx.y;
  int n0 = sp * (HW / NSPLIT);
  const float* qb = qkv2 + (i64)(h * CH) * HW + n0;
  const float* kb = qkv2 + (i64)(DIM + h * CH) * HW + n0;
  int tid = threadIdx.x;
  int c0 = (tid >> 4) * 3, d0 = (tid & 15) * 3;
  float acc[3][3] = {};
  for (int nn = 0; nn < 256; nn += 128) {
    for (int l = tid; l < 48 * 32; l += 256) {
      int r = l >> 5, j = (l & 31) * 4;
      *(float4*)&qs[r][j] = *(const float4*)(qb + (i64)r * HW + nn + j);
      *(float4*)&ks[r][j] = *(const float4*)(kb + (i64)r * HW + nn + j);
    }
    __syncthreads();
    #pragma unroll 2
    for (int j = 0; j < 128; j += 4) {
      float qv[3][4], kv[3][4];
      #pragma unroll
      for (int i = 0; i < 3; ++i) {
        float4 t = *(const float4*)&qs[c0 + i][j];
        qv[i][0] = t.x; qv[i][1] = t.y; qv[i][2] = t.z; qv[i][3] = t.w;
        float4 u = *(const float4*)&ks[d0 + i][j];
        kv[i][0] = u.x; kv[i][1] = u.y; kv[i][2] = u.z; kv[i][3] = u.w;
      }
      #pragma unroll
      for (int i = 0; i < 3; ++i)
        #pragma unroll
        for (int jj = 0; jj < 3; ++jj)
          #pragma unroll
          for (int e = 0; e < 4; ++e)
            acc[i][jj] += qv[i][e] * kv[jj][e];
    }
    __syncthreads();
  }
  float* pp = part + ((i64)(h * NSPLIT) + sp) * 2304;
  #pragma unroll
  for (int i = 0; i < 3; ++i)
    #pragma unroll
    for (int jj = 0; jj < 3; ++jj)
      pp[(c0 + i) * 48 + d0 + jj] = acc[i][jj];
}

// ---------------- reduce partials, scale, softmax ----------------
__global__ __launch_bounds__(64) void attn_sm_kernel(const float* __restrict__ part,
    const float* __restrict__ inv, const float* __restrict__ temp,
    float* __restrict__ attn) {
  int h = blockIdx.x, c = blockIdx.y;
  int d = threadIdx.x;
  float logit = -1e30f;
  if (d < CH) {
    float s = 0.f;
    for (int sp = 0; sp < NSPLIT; ++sp)
      s += part[((i64)(h * NSPLIT) + sp) * 2304 + c * 48 + d];
    logit = s * inv[h * CH + c] * inv[DIM + h * CH + d] * temp[h];
  }
  float m = logit;
  #pragma unroll
  for (int mask = 32; mask; mask >>= 1) m = fmaxf(m, __shfl_xor(m, mask));
  float e = (d < CH) ? expf(logit - m) : 0.f;
  float ssum = e;
  #pragma unroll
  for (int mask = 32; mask; mask >>= 1) ssum += __shfl_xor(ssum, mask);
  if (d < CH) attn[(i64)h * 2304 + c * 48 + d] = e / ssum;
}

// ---------------- out = attn @ v ; writes bf16 pixel-major [N,192] ----------------
__global__ __launch_bounds__(256) void attn_v_kernel(const float* __restrict__ qkv2,
    const float* __restrict__ attnm, u16* __restrict__ outT) {
  __shared__ float as[CH * CH];
  int h = blockIdx.x, tile = blockIdx.y;
  for (int l = threadIdx.x; l < CH * CH; l += 256) as[l] = attnm[(i64)h * 2304 + l];
  __syncthreads();
  int n = tile * 256 + threadIdx.x;
  const float* vb = qkv2 + (i64)(2 * DIM + h * CH) * HW + n;
  float vreg[CH];
  #pragma unroll
  for (int d = 0; d < CH; ++d) vreg[d] = vb[(i64)d * HW];
  u16* ob = outT + (i64)n * DIM + h * CH;
  #pragma unroll 2
  for (int c = 0; c < CH; c += 4) {
    float a0 = 0.f, a1 = 0.f, a2 = 0.f, a3 = 0.f;
    const float* r0 = &as[(c + 0) * CH];
    const float* r1 = &as[(c + 1) * CH];
    const float* r2 = &as[(c + 2) * CH];
    const float* r3 = &as[(c + 3) * CH];
    #pragma unroll
    for (int d = 0; d < CH; ++d) {
      float vv = vreg[d];
      a0 += r0[d] * vv; a1 += r1[d] * vv; a2 += r2[d] * vv; a3 += r3[d] * vv;
    }
    ushort4 u; u.x = f2bf(a0); u.y = f2bf(a1); u.z = f2bf(a2); u.w = f2bf(a3);
    *(ushort4*)(ob + c) = u;
  }
}

// ---------------- fused FFN dwconv3x3 + exact-GELU gating (fp32 out [510,N]) ----
__global__ __launch_bounds__(256) void dwgate_kernel(const float* __restrict__ h1,
    const float* __restrict__ w9, const float* __restrict__ bs,
    float* __restrict__ outg) {
  int idx = blockIdx.x * 256 + threadIdx.x;
  if (idx >= HID * HW) return;
  int c = idx >> 14, rem = idx & 16383;
  int yy = rem >> 7, xx = rem & 127;
  const float* w1 = w9 + c * 9;
  const float* w2 = w9 + (i64)(c + HID) * 9;
  const float* i1 = h1 + (i64)c * HW;
  const float* i2 = h1 + (i64)(c + HID) * HW;
  float a1 = bs[c], a2 = bs[c + HID];
  #pragma unroll
  for (int dy = -1; dy <= 1; ++dy) {
    int iy = yy + dy;
    if (iy < 0 || iy >= IMG_H) continue;
    #pragma unroll
    for (int dx = -1; dx <= 1; ++dx) {
      int ix = xx + dx;
      if (ix < 0 || ix >= IMG_W) continue;
      int off = iy * IMG_W + ix;
      int wi = (dy + 1) * 3 + (dx + 1);
      a1 += w1[wi] * i1[off];
      a2 += w2[wi] * i2[off];
    }
  }
  float g = 0.5f * a1 * (1.f + erff(a1 * 0.70710678118654752f));
  outg[idx] = g * a2;
}

// ---------------- fp32 [510,N] -> bf16 [N,512] (pad K to 512 with zeros) -----
__global__ __launch_bounds__(256) void transp_kernel(const float* __restrict__ in,
    u16* __restrict__ out) {
  __shared__ u16 t[64][136];
  int p0 = blockIdx.x * 64;
  int tid = threadIdx.x;
  for (int c0 = 0; c0 < 512; c0 += 128) {
    #pragma unroll 4
    for (int i = 0; i < 32; ++i) {
      int c = (tid >> 6) + i * 4;
      int p = tid & 63;
      int cc = c0 + c;
      float v = (cc < HID) ? in[(i64)cc * HW + p0 + p] : 0.f;
      t[p][c] = f2bf(v);
    }
    __syncthreads();
    #pragma unroll
    for (int i = 0; i < 4; ++i) {
      int p = (tid >> 4) + i * 16;
      int c8 = (tid & 15) * 8;
      *(uint4*)(out + (i64)(p0 + p) * 512 + c0 + c8) = *(const uint4*)&t[p][c8];
    }
    __syncthreads();
  }
}

extern "C" void kernel_launch(void* const* d_in, const int* in_sizes, int n_in,
                              void* d_out, int out_size, void* d_ws, size_t ws_size,
                              hipStream_t stream) {
  const float* x        = (const float*)d_in[0];
  const float* ln1_w    = (const float*)d_in[1];
  const float* ln1_b    = (const float*)d_in[2];
  const float* qkv_w    = (const float*)d_in[3];
  const float* qkv_b    = (const float*)d_in[4];
  const float* qkv_dw_w = (const float*)d_in[5];
  const float* qkv_dw_b = (const float*)d_in[6];
  const float* temp     = (const float*)d_in[7];
  const float* proj_w   = (const float*)d_in[8];
  const float* proj_b   = (const float*)d_in[9];
  const float* ln2_w    = (const float*)d_in[10];
  const float* ln2_b    = (const float*)d_in[11];
  const float* pin_w    = (const float*)d_in[12];
  const float* pin_b    = (const float*)d_in[13];
  const float* dw_w     = (const float*)d_in[14];
  const float* dw_b     = (const float*)d_in[15];
  const float* pout_w   = (const float*)d_in[16];
  const float* pout_b   = (const float*)d_in[17];
  float* out = (float*)d_out;
  float* ws  = (float*)d_ws;

  // workspace layout
  float* buf1f = ws;                               // 1020*16384 fp32 (qkv1 / h1)
  float* buf2f = buf1f + (i64)H2 * HW;             // 576*16384 fp32 (qkv2 / gated)
  u16*   yT    = (u16*)(buf2f + (i64)OQKV * HW);   // 16384*192 bf16
  u16*   Wq    = yT + (i64)HW * DIM;               // 640*192
  u16*   Wpj   = Wq + 640 * 192;                   // 256*192
  u16*   Wpi   = Wpj + 256 * 192;                  // 1024*192
  u16*   Wpo   = Wpi + 1024 * 192;                 // 256*512
  float* invn  = (float*)(Wpo + 256 * 512);        // 384
  float* attnm = invn + 384;                       // 9216
  float* part  = attnm + 9216;                     // 4*64*2304
  u16* attnoutT = (u16*)buf1f;
  u16* gatedT   = (u16*)buf1f;
  size_t need = (size_t)((char*)(part + 589824) - (char*)ws);
  if (ws_size < need) return;

  wconv_kernel<<<(640 * 192 + 255) / 256, 256, 0, stream>>>(qkv_w, Wq, OQKV, DIM, DIM, 640 * 192);
  wconv_kernel<<<(256 * 192 + 255) / 256, 256, 0, stream>>>(proj_w, Wpj, DIM, DIM, DIM, 256 * 192);
  wconv_kernel<<<(1024 * 192 + 255) / 256, 256, 0, stream>>>(pin_w, Wpi, H2, DIM, DIM, 1024 * 192);
  wconv_kernel<<<(256 * 512 + 255) / 256, 256, 0, stream>>>(pout_w, Wpo, DIM, HID, 512, 256 * 512);

  for (int b = 0; b < NB; ++b) {
    const float* xb = x + (i64)b * DIM * HW;
    float* outb = out + (i64)b * DIM * HW;

    // ---- attention branch ----
    ln_kernel<<<HW / LNP, 256, 0, stream>>>(xb, ln1_w, ln1_b, yT);
    gemm_bf16<<<dim3(HW / 128, 640 / 128), 256, 0, stream>>>(Wq, qkv_b, yT, nullptr, buf1f, OQKV, DIM);
    dwconv_kernel<<<(OQKV * HW) / 256, 256, 0, stream>>>(buf1f, qkv_dw_w, qkv_dw_b, buf2f, OQKV);
    l2inv_kernel<<<2 * DIM, 256, 0, stream>>>(buf2f, invn);
    attn_qk_kernel<<<dim3(NHEADS, NSPLIT), 256, 0, stream>>>(buf2f, part);
    attn_sm_kernel<<<dim3(NHEADS, CH), 64, 0, stream>>>(part, invn, temp, attnm);
    attn_v_kernel<<<dim3(NHEADS, HW / 256), 256, 0, stream>>>(buf2f, attnm, attnoutT);
    gemm_bf16<<<dim3(HW / 128, 256 / 128), 256, 0, stream>>>(Wpj, proj_b, attnoutT, xb, outb, DIM, DIM);

    // ---- FFN branch ----
    ln_kernel<<<HW / LNP, 256, 0, stream>>>(outb, ln2_w, ln2_b, yT);
    gemm_bf16<<<dim3(HW / 128, 1024 / 128), 256, 0, stream>>>(Wpi, pin_b, yT, nullptr, buf1f, H2, DIM);
    dwgate_kernel<<<(HID * HW) / 256, 256, 0, stream>>>(buf1f, dw_w, dw_b, buf2f);
    transp_kernel<<<HW / 64, 256, 0, stream>>>(buf2f, gatedT);
    gemm_bf16<<<dim3(HW / 128, 256 / 128), 256, 0, stream>>>(Wpo, pout_b, buf2f != nullptr ? gatedT : gatedT, outb, outb, DIM, 512);
  }
}

// Round 4
// 841.478 us; speedup vs baseline: 2.4980x; 1.4399x over previous
//
#include <hip/hip_runtime.h>
#include <math.h>

typedef long long i64;
typedef unsigned short u16;
typedef unsigned int u32;

#define HW 16384
#define DIM 192
#define NHEADS 4
#define CH 48
#define OQKV 576
#define HID 510
#define H2 1020
#define NB 4
#define NSPLIT 64

typedef __attribute__((ext_vector_type(8))) short short8v;
typedef __attribute__((ext_vector_type(4))) float float4v;

__device__ __forceinline__ u16 f2bf(float f) {
  union { float f; u32 u; } v; v.f = f;
  u32 r = v.u + 0x7FFF + ((v.u >> 16) & 1);
  return (u16)(r >> 16);
}
__device__ __forceinline__ float bflo(u32 w) {
  union { u32 u; float f; } v; v.u = w << 16; return v.f;
}
__device__ __forceinline__ float bfhi(u32 w) {
  union { u32 u; float f; } v; v.u = w & 0xFFFF0000u; return v.f;
}
__device__ __forceinline__ float gelu_f(float x) {
  float y = 0.7978845608f * (x + 0.044715f * x * x * x);
  float ay = fabsf(y);
  float e = __expf(-2.f * ay);
  float t = (1.f - e) / (1.f + e);
  t = (y < 0.f) ? -t : t;
  return 0.5f * x * (1.f + t);
}

#define GLL16(gp, lp) __builtin_amdgcn_global_load_lds( \
    (const __attribute__((address_space(1))) u32*)(gp), \
    (__attribute__((address_space(3))) u32*)(lp), 16, 0, 0)

// ---------------- LayerNorm over channels; writes bf16 pixel-major [N,192] ----
#define LNP 32
#define LNG 8
#define LNC 24
__global__ __launch_bounds__(256) void ln_kernel(const float* __restrict__ x,
    const float* __restrict__ w, const float* __restrict__ b, u16* __restrict__ yT) {
  __shared__ float red[2][LNG][LNP];
  __shared__ float murs[2][LNP];
  int tid = threadIdx.x;
  int g = tid >> 5;
  int p = tid & 31;
  int pix = blockIdx.x * LNP + p;
  const float* xp = x + pix;
  float v[LNC];
  float s = 0.f, ss = 0.f;
  #pragma unroll
  for (int i = 0; i < LNC; ++i) {
    float t = xp[(i64)(g * LNC + i) * HW];
    v[i] = t; s += t; ss += t * t;
  }
  red[0][g][p] = s; red[1][g][p] = ss;
  __syncthreads();
  if (tid < LNP) {
    float S = 0.f, SS = 0.f;
    #pragma unroll
    for (int gg = 0; gg < LNG; ++gg) { S += red[0][gg][tid]; SS += red[1][gg][tid]; }
    float mu = S * (1.f / DIM);
    float var = SS * (1.f / DIM) - mu * mu;
    murs[0][tid] = mu;
    murs[1][tid] = rsqrtf(var + 1e-5f);
  }
  __syncthreads();
  float mu = murs[0][p], rs = murs[1][p];
  u16* yp = yT + (i64)pix * DIM + g * LNC;
  #pragma unroll
  for (int i = 0; i < LNC; i += 4) {
    int c = g * LNC + i;
    ushort4 u;
    u.x = f2bf((v[i + 0] - mu) * rs * w[c + 0] + b[c + 0]);
    u.y = f2bf((v[i + 1] - mu) * rs * w[c + 1] + b[c + 1]);
    u.z = f2bf((v[i + 2] - mu) * rs * w[c + 2] + b[c + 2]);
    u.w = f2bf((v[i + 3] - mu) * rs * w[c + 3] + b[c + 3]);
    *(ushort4*)(yp + i) = u;
  }
}

// ---------------- weight fp32 [O,C] -> bf16 [Mpad,Kpad] zero-padded ----------
__global__ __launch_bounds__(256) void wconv_kernel(const float* __restrict__ W,
    u16* __restrict__ Wb, int O, int C, int Kpad, int total) {
  int idx = blockIdx.x * 256 + threadIdx.x;
  if (idx >= total) return;
  int r = idx / Kpad, c = idx - r * Kpad;
  float v = (r < O && c < C) ? W[(i64)r * C + c] : 0.f;
  Wb[idx] = f2bf(v);
}

// ---------------- bf16 MFMA GEMM: Out[o,n] = bias[o] + sum_k A[o,k]*B[n,k] ----
// OutB != null -> write bf16 [o][n]; else fp32 with optional residual.
__global__ __launch_bounds__(256) void gemm_bf16(const u16* __restrict__ A,
    const float* __restrict__ bias, const u16* __restrict__ B,
    const float* __restrict__ Res, float* __restrict__ Out,
    u16* __restrict__ OutB, int O, int K) {
  __shared__ __align__(16) u16 lds[2 * 128 * 64];
  int tid = threadIdx.x;
  int lane = tid & 63, wave = tid >> 6;
  int wm = (wave >> 1) * 64, wn = (wave & 1) * 64;
  int obase = blockIdx.y * 128, nbase = blockIdx.x * 128;
  float4v acc[4][4];
  #pragma unroll
  for (int m = 0; m < 4; ++m)
    #pragma unroll
    for (int n = 0; n < 4; ++n) acc[m][n] = (float4v){0.f, 0.f, 0.f, 0.f};

  const u16* Abase = A + (i64)obase * K;
  const u16* Bbase = B + (i64)nbase * K;
  char* ldsA = (char*)&lds[0];
  char* ldsB = (char*)&lds[8192];
  int srow = wave * 8 + (lane >> 3);
  int sj = lane & 7;

  for (int k0 = 0; k0 < K; k0 += 64) {
    #pragma unroll
    for (int iss = 0; iss < 4; ++iss) {
      int r = iss * 32 + srow;
      int kb = sj ^ (r & 7);
      GLL16(Abase + (i64)r * K + k0 + kb * 8, ldsA + iss * 4096 + wave * 1024);
      GLL16(Bbase + (i64)r * K + k0 + kb * 8, ldsB + iss * 4096 + wave * 1024);
    }
    __syncthreads();
    #pragma unroll
    for (int kk = 0; kk < 2; ++kk) {
      short8v af[4], bfr[4];
      #pragma unroll
      for (int m = 0; m < 4; ++m) {
        int r = wm + m * 16 + (lane & 15);
        int kb = kk * 4 + (lane >> 4);
        af[m] = *(const short8v*)(ldsA + r * 128 + ((kb ^ (r & 7)) << 4));
      }
      #pragma unroll
      for (int n = 0; n < 4; ++n) {
        int r = wn + n * 16 + (lane & 15);
        int kb = kk * 4 + (lane >> 4);
        bfr[n] = *(const short8v*)(ldsB + r * 128 + ((kb ^ (r & 7)) << 4));
      }
      #pragma unroll
      for (int m = 0; m < 4; ++m)
        #pragma unroll
        for (int n = 0; n < 4; ++n)
          acc[m][n] = __builtin_amdgcn_mfma_f32_16x16x32_bf16(af[m], bfr[n], acc[m][n], 0, 0, 0);
    }
    __syncthreads();
  }

  int rowq = lane >> 4, coln = lane & 15;
  #pragma unroll
  for (int m = 0; m < 4; ++m) {
    #pragma unroll
    for (int reg = 0; reg < 4; ++reg) {
      int o = obase + wm + m * 16 + rowq * 4 + reg;
      if (o >= O) continue;
      float bv = bias[o];
      #pragma unroll
      for (int n = 0; n < 4; ++n) {
        int nn = nbase + wn + n * 16 + coln;
        float v = acc[m][n][reg] + bv;
        if (OutB) {
          OutB[(i64)o * HW + nn] = f2bf(v);
        } else {
          if (Res) v += Res[(i64)o * HW + nn];
          Out[(i64)o * HW + nn] = v;
        }
      }
    }
  }
}

// ---------------- depthwise 3x3, bf16 in [C,HW], fp32 out [C,HW] -------------
// grid (C/64, 128 rows); thread: 8 ch x 4 px.
__global__ __launch_bounds__(256) void dwconv_bf16(const u16* __restrict__ in,
    const float* __restrict__ w9, const float* __restrict__ bs,
    float* __restrict__ out) {
  int q = threadIdx.x & 31;        // px quad (x = 4q..4q+3)
  int grp = threadIdx.x >> 5;      // 0..7
  int y = blockIdx.y;
  int c0 = blockIdx.x * 64 + grp * 8;
  int xb = q * 4;
  #pragma unroll
  for (int i = 0; i < 8; ++i) {
    int c = c0 + i;
    const float* wp = w9 + c * 9;
    float bv = bs[c];
    float a0 = bv, a1 = bv, a2 = bv, a3 = bv;
    const u16* chan = in + (i64)c * HW;
    #pragma unroll
    for (int dy = -1; dy <= 1; ++dy) {
      int yy = y + dy;
      if (yy < 0 || yy >= 128) continue;
      uint4 raw = *(const uint4*)(chan + yy * 128 + xb - 2);
      float f1 = bfhi(raw.x);
      float f2 = bflo(raw.y), f3 = bfhi(raw.y);
      float f4 = bflo(raw.z), f5 = bfhi(raw.z);
      float f6 = bflo(raw.w);
      if (q == 0) f1 = 0.f;
      if (q == 31) f6 = 0.f;
      float wa = wp[(dy + 1) * 3 + 0], wb = wp[(dy + 1) * 3 + 1], wc = wp[(dy + 1) * 3 + 2];
      a0 += wa * f1 + wb * f2 + wc * f3;
      a1 += wa * f2 + wb * f3 + wc * f4;
      a2 += wa * f3 + wb * f4 + wc * f5;
      a3 += wa * f4 + wb * f5 + wc * f6;
    }
    *(float4*)(out + (i64)c * HW + y * 128 + xb) = make_float4(a0, a1, a2, a3);
  }
}

// ---------------- fused FFN dw3x3 + GELU gate; bf16 in [1020,HW] -> bf16 [N,512]
// grid (8, 128 rows); thread: 8 out-ch x 4 px; writes [pixel][512] padded.
__global__ __launch_bounds__(256) void dwgate_bf16(const u16* __restrict__ h1,
    const float* __restrict__ w9, const float* __restrict__ bs,
    u16* __restrict__ og) {
  int q = threadIdx.x & 31;
  int grp = threadIdx.x >> 5;
  int y = blockIdx.y;
  int c0 = blockIdx.x * 64 + grp * 8;
  int xb = q * 4;
  float res[4][8];
  #pragma unroll
  for (int i = 0; i < 8; ++i) {
    int c = c0 + i;
    bool valid = (c < HID);
    float b1 = valid ? bs[c] : 0.f;
    float b2 = valid ? bs[c + HID] : 0.f;
    float a0 = b1, a1 = b1, a2 = b1, a3 = b1;
    float g0 = b2, g1 = b2, g2 = b2, g3 = b2;
    if (valid) {
      const float* wp1 = w9 + c * 9;
      const float* wp2 = w9 + (i64)(c + HID) * 9;
      const u16* ch1 = h1 + (i64)c * HW;
      const u16* ch2 = h1 + (i64)(c + HID) * HW;
      #pragma unroll
      for (int dy = -1; dy <= 1; ++dy) {
        int yy = y + dy;
        if (yy < 0 || yy >= 128) continue;
        {
          uint4 raw = *(const uint4*)(ch1 + yy * 128 + xb - 2);
          float f1 = bfhi(raw.x);
          float f2 = bflo(raw.y), f3 = bfhi(raw.y);
          float f4 = bflo(raw.z), f5 = bfhi(raw.z);
          float f6 = bflo(raw.w);
          if (q == 0) f1 = 0.f;
          if (q == 31) f6 = 0.f;
          float wa = wp1[(dy + 1) * 3 + 0], wb = wp1[(dy + 1) * 3 + 1], wc = wp1[(dy + 1) * 3 + 2];
          a0 += wa * f1 + wb * f2 + wc * f3;
          a1 += wa * f2 + wb * f3 + wc * f4;
          a2 += wa * f3 + wb * f4 + wc * f5;
          a3 += wa * f4 + wb * f5 + wc * f6;
        }
        {
          uint4 raw = *(const uint4*)(ch2 + yy * 128 + xb - 2);
          float f1 = bfhi(raw.x);
          float f2 = bflo(raw.y), f3 = bfhi(raw.y);
          float f4 = bflo(raw.z), f5 = bfhi(raw.z);
          float f6 = bflo(raw.w);
          if (q == 0) f1 = 0.f;
          if (q == 31) f6 = 0.f;
          float wa = wp2[(dy + 1) * 3 + 0], wb = wp2[(dy + 1) * 3 + 1], wc = wp2[(dy + 1) * 3 + 2];
          g0 += wa * f1 + wb * f2 + wc * f3;
          g1 += wa * f2 + wb * f3 + wc * f4;
          g2 += wa * f3 + wb * f4 + wc * f5;
          g3 += wa * f4 + wb * f5 + wc * f6;
        }
      }
    }
    res[0][i] = valid ? gelu_f(a0) * g0 : 0.f;
    res[1][i] = valid ? gelu_f(a1) * g1 : 0.f;
    res[2][i] = valid ? gelu_f(a2) * g2 : 0.f;
    res[3][i] = valid ? gelu_f(a3) * g3 : 0.f;
  }
  #pragma unroll
  for (int j = 0; j < 4; ++j) {
    uint4 o;
    o.x = (u32)f2bf(res[j][0]) | ((u32)f2bf(res[j][1]) << 16);
    o.y = (u32)f2bf(res[j][2]) | ((u32)f2bf(res[j][3]) << 16);
    o.z = (u32)f2bf(res[j][4]) | ((u32)f2bf(res[j][5]) << 16);
    o.w = (u32)f2bf(res[j][6]) | ((u32)f2bf(res[j][7]) << 16);
    *(uint4*)(og + ((i64)(y * 128 + xb + j)) * 512 + c0) = o;
  }
}

// ---------------- q @ k^T split-K partials + per-channel sq-norm partials -----
__global__ __launch_bounds__(256) void attn_qk_kernel(const float* __restrict__ qkv2,
    float* __restrict__ part, float* __restrict__ partN) {
  __shared__ float qs[48][128];
  __shared__ float ks[48][128];
  int h = blockIdx.x, sp = blockIdx.y;
  int n0 = sp * (HW / NSPLIT);
  const float* qb = qkv2 + (i64)(h * CH) * HW + n0;
  const float* kb = qkv2 + (i64)(DIM + h * CH) * HW + n0;
  int tid = threadIdx.x;
  int c0 = (tid >> 4) * 3, d0 = (tid & 15) * 3;
  bool isq = (tid & 15) == 0;
  bool isk = (tid >> 4) == 0;
  float acc[3][3] = {};
  float qn[3] = {}, kn[3] = {};
  for (int nn = 0; nn < 256; nn += 128) {
    for (int l = tid; l < 48 * 32; l += 256) {
      int r = l >> 5, j = (l & 31) * 4;
      *(float4*)&qs[r][j] = *(const float4*)(qb + (i64)r * HW + nn + j);
      *(float4*)&ks[r][j] = *(const float4*)(kb + (i64)r * HW + nn + j);
    }
    __syncthreads();
    #pragma unroll 2
    for (int j = 0; j < 128; j += 4) {
      float qv[3][4], kv[3][4];
      #pragma unroll
      for (int i = 0; i < 3; ++i) {
        float4 t = *(const float4*)&qs[c0 + i][j];
        qv[i][0] = t.x; qv[i][1] = t.y; qv[i][2] = t.z; qv[i][3] = t.w;
        float4 u = *(const float4*)&ks[d0 + i][j];
        kv[i][0] = u.x; kv[i][1] = u.y; kv[i][2] = u.z; kv[i][3] = u.w;
      }
      #pragma unroll
      for (int i = 0; i < 3; ++i)
        #pragma unroll
        for (int jj = 0; jj < 3; ++jj)
          #pragma unroll
          for (int e = 0; e < 4; ++e)
            acc[i][jj] += qv[i][e] * kv[jj][e];
      if (isq) {
        #pragma unroll
        for (int i = 0; i < 3; ++i)
          #pragma unroll
          for (int e = 0; e < 4; ++e) qn[i] += qv[i][e] * qv[i][e];
      }
      if (isk) {
        #pragma unroll
        for (int i = 0; i < 3; ++i)
          #pragma unroll
          for (int e = 0; e < 4; ++e) kn[i] += kv[i][e] * kv[i][e];
      }
    }
    __syncthreads();
  }
  float* pp = part + ((i64)(h * NSPLIT) + sp) * 2304;
  #pragma unroll
  for (int i = 0; i < 3; ++i)
    #pragma unroll
    for (int jj = 0; jj < 3; ++jj)
      pp[(c0 + i) * 48 + d0 + jj] = acc[i][jj];
  float* pn = partN + ((i64)(h * NSPLIT) + sp) * 96;
  if (isq) {
    #pragma unroll
    for (int i = 0; i < 3; ++i) pn[c0 + i] = qn[i];
  }
  if (isk) {
    #pragma unroll
    for (int i = 0; i < 3; ++i) pn[48 + d0 + i] = kn[i];
  }
}

// ---------------- reduce norm partials -> inv[384] ---------------------------
__global__ __launch_bounds__(384) void norm_reduce(const float* __restrict__ partN,
    float* __restrict__ inv) {
  int j = threadIdx.x;           // 0..383
  int h = j / 96, r = j - h * 96;
  float s = 0.f;
  for (int sp = 0; sp < NSPLIT; ++sp) s += partN[((i64)(h * NSPLIT) + sp) * 96 + r];
  float iv = 1.f / fmaxf(sqrtf(s), 1e-12f);
  int dst = (r < 48) ? (h * CH + r) : (DIM + h * CH + (r - 48));
  inv[dst] = iv;
}

// ---------------- reduce partials, scale, softmax ----------------
__global__ __launch_bounds__(64) void attn_sm_kernel(const float* __restrict__ part,
    const float* __restrict__ inv, const float* __restrict__ temp,
    float* __restrict__ attn) {
  int h = blockIdx.x, c = blockIdx.y;
  int d = threadIdx.x;
  float logit = -1e30f;
  if (d < CH) {
    float s = 0.f;
    for (int sp = 0; sp < NSPLIT; ++sp)
      s += part[((i64)(h * NSPLIT) + sp) * 2304 + c * 48 + d];
    logit = s * inv[h * CH + c] * inv[DIM + h * CH + d] * temp[h];
  }
  float m = logit;
  #pragma unroll
  for (int mask = 32; mask; mask >>= 1) m = fmaxf(m, __shfl_xor(m, mask));
  float e = (d < CH) ? expf(logit - m) : 0.f;
  float ssum = e;
  #pragma unroll
  for (int mask = 32; mask; mask >>= 1) ssum += __shfl_xor(ssum, mask);
  if (d < CH) attn[(i64)h * 2304 + c * 48 + d] = e / ssum;
}

// ---------------- out = attn @ v ; writes bf16 pixel-major [N,192] -----------
__global__ __launch_bounds__(256) void attn_v_kernel(const float* __restrict__ qkv2,
    const float* __restrict__ attnm, u16* __restrict__ outT) {
  __shared__ float as[CH * CH];
  int h = blockIdx.x, tile = blockIdx.y;
  for (int l = threadIdx.x; l < CH * CH; l += 256) as[l] = attnm[(i64)h * 2304 + l];
  __syncthreads();
  int n = tile * 256 + threadIdx.x;
  const float* vb = qkv2 + (i64)(2 * DIM + h * CH) * HW + n;
  float vreg[CH];
  #pragma unroll
  for (int d = 0; d < CH; ++d) vreg[d] = vb[(i64)d * HW];
  u16* ob = outT + (i64)n * DIM + h * CH;
  #pragma unroll 2
  for (int c = 0; c < CH; c += 4) {
    float a0 = 0.f, a1 = 0.f, a2 = 0.f, a3 = 0.f;
    const float* r0 = &as[(c + 0) * CH];
    const float* r1 = &as[(c + 1) * CH];
    const float* r2 = &as[(c + 2) * CH];
    const float* r3 = &as[(c + 3) * CH];
    #pragma unroll
    for (int d = 0; d < CH; ++d) {
      float vv = vreg[d];
      a0 += r0[d] * vv; a1 += r1[d] * vv; a2 += r2[d] * vv; a3 += r3[d] * vv;
    }
    ushort4 u; u.x = f2bf(a0); u.y = f2bf(a1); u.z = f2bf(a2); u.w = f2bf(a3);
    *(ushort4*)(ob + c) = u;
  }
}

extern "C" void kernel_launch(void* const* d_in, const int* in_sizes, int n_in,
                              void* d_out, int out_size, void* d_ws, size_t ws_size,
                              hipStream_t stream) {
  const float* x        = (const float*)d_in[0];
  const float* ln1_w    = (const float*)d_in[1];
  const float* ln1_b    = (const float*)d_in[2];
  const float* qkv_w    = (const float*)d_in[3];
  const float* qkv_b    = (const float*)d_in[4];
  const float* qkv_dw_w = (const float*)d_in[5];
  const float* qkv_dw_b = (const float*)d_in[6];
  const float* temp     = (const float*)d_in[7];
  const float* proj_w   = (const float*)d_in[8];
  const float* proj_b   = (const float*)d_in[9];
  const float* ln2_w    = (const float*)d_in[10];
  const float* ln2_b    = (const float*)d_in[11];
  const float* pin_w    = (const float*)d_in[12];
  const float* pin_b    = (const float*)d_in[13];
  const float* dw_w     = (const float*)d_in[14];
  const float* dw_b     = (const float*)d_in[15];
  const float* pout_w   = (const float*)d_in[16];
  const float* pout_b   = (const float*)d_in[17];
  float* out = (float*)d_out;
  char* ws = (char*)d_ws;

  // workspace layout (weights first so bufA-4B reads stay in-bounds)
  u16* Wq   = (u16*)ws;                      // 640*192
  u16* Wpj  = Wq + 640 * 192;                // 256*192
  u16* Wpi  = Wpj + 256 * 192;               // 1024*192
  u16* Wpo  = Wpi + 1024 * 192;              // 256*512
  float* invn  = (float*)(Wpo + 256 * 512);  // 384
  float* attnm = invn + 384;                 // 9216
  float* part  = attnm + 9216;               // 4*64*2304 = 589824
  float* partN = part + 589824;              // 4*64*96   = 24576
  u16* yT   = (u16*)(partN + 24576);         // HW*192
  u16* bufA = yT + (i64)HW * DIM;            // 1020*HW bf16 (qkv1/h1/attnoutT)
  float* buf2f = (float*)(bufA + (i64)H2 * HW); // 576*HW fp32 (qkv2) / gatedT
  u16* attnoutT = bufA;
  u16* gatedT = (u16*)buf2f;
  size_t need = (size_t)((char*)(buf2f + (i64)OQKV * HW) - ws);
  if (ws_size < need) return;

  wconv_kernel<<<(640 * 192 + 255) / 256, 256, 0, stream>>>(qkv_w, Wq, OQKV, DIM, DIM, 640 * 192);
  wconv_kernel<<<(256 * 192 + 255) / 256, 256, 0, stream>>>(proj_w, Wpj, DIM, DIM, DIM, 256 * 192);
  wconv_kernel<<<(1024 * 192 + 255) / 256, 256, 0, stream>>>(pin_w, Wpi, H2, DIM, DIM, 1024 * 192);
  wconv_kernel<<<(256 * 512 + 255) / 256, 256, 0, stream>>>(pout_w, Wpo, DIM, HID, 512, 256 * 512);

  for (int b = 0; b < NB; ++b) {
    const float* xb = x + (i64)b * DIM * HW;
    float* outb = out + (i64)b * DIM * HW;

    // ---- attention branch ----
    ln_kernel<<<HW / LNP, 256, 0, stream>>>(xb, ln1_w, ln1_b, yT);
    gemm_bf16<<<dim3(HW / 128, 640 / 128), 256, 0, stream>>>(Wq, qkv_b, yT, nullptr, nullptr, bufA, OQKV, DIM);
    dwconv_bf16<<<dim3(OQKV / 64, 128), 256, 0, stream>>>(bufA, qkv_dw_w, qkv_dw_b, buf2f);
    attn_qk_kernel<<<dim3(NHEADS, NSPLIT), 256, 0, stream>>>(buf2f, part, partN);
    norm_reduce<<<1, 384, 0, stream>>>(partN, invn);
    attn_sm_kernel<<<dim3(NHEADS, CH), 64, 0, stream>>>(part, invn, temp, attnm);
    attn_v_kernel<<<dim3(NHEADS, HW / 256), 256, 0, stream>>>(buf2f, attnm, attnoutT);
    gemm_bf16<<<dim3(HW / 128, 256 / 128), 256, 0, stream>>>(Wpj, proj_b, attnoutT, xb, outb, nullptr, DIM, DIM);

    // ---- FFN branch ----
    ln_kernel<<<HW / LNP, 256, 0, stream>>>(outb, ln2_w, ln2_b, yT);
    gemm_bf16<<<dim3(HW / 128, 1024 / 128), 256, 0, stream>>>(Wpi, pin_b, yT, nullptr, nullptr, bufA, H2, DIM);
    dwgate_bf16<<<dim3(8, 128), 256, 0, stream>>>(bufA, dw_w, dw_b, gatedT);
    gemm_bf16<<<dim3(HW / 128, 256 / 128), 256, 0, stream>>>(Wpo, pout_b, gatedT, outb, outb, nullptr, DIM, 512);
  }
}